// Round 1
// baseline (1114.987 us; speedup 1.0000x reference)
//
#include <hip/hip_runtime.h>
#include <cstdint>
#include <cstddef>

#define TDIM 4096
#define HDIM 2048
#define FDIM 1408
#define NEXP 8
#define NSLOT (TDIM * 2)

typedef _Float16 half8 __attribute__((ext_vector_type(8)));
typedef _Float16 half4 __attribute__((ext_vector_type(4)));
typedef float floatx4 __attribute__((ext_vector_type(4)));

// ---------------- ws layout (bytes) ----------------
static constexpr size_t WS_XB     = 0;                                  // f16 [TDIM][HDIM]
static constexpr size_t WS_ACT_S  = WS_XB    + (size_t)TDIM * HDIM * 2; // f16 [TDIM][FDIM]
static constexpr size_t WS_ACT_R  = WS_ACT_S + (size_t)TDIM * FDIM * 2; // f16 [NSLOT][FDIM]
static constexpr size_t WS_TOKE   = WS_ACT_R + (size_t)NSLOT * FDIM * 2;// int  [TDIM][2]
static constexpr size_t WS_TOKG   = WS_TOKE  + (size_t)TDIM * 2 * 4;    // f32  [TDIM][2]
static constexpr size_t WS_SLOTT  = WS_TOKG  + (size_t)TDIM * 2 * 4;    // int  [NSLOT]
static constexpr size_t WS_SLOTG  = WS_SLOTT + (size_t)NSLOT * 4;       // f32  [NSLOT]
static constexpr size_t WS_COUNTS = WS_SLOTG + (size_t)NSLOT * 4;       // int  [NEXP] (64B slot)
static constexpr size_t WS_FILL   = WS_COUNTS + 64;                     // int  [NEXP] (64B slot)
static constexpr size_t WS_OFFS   = WS_FILL   + 64;                     // int  [NEXP]

// ---------------- small kernels ----------------

__global__ void zero_meta_kernel(int* __restrict__ counts) {
  // zeroes counts (16 ints incl pad) + fill (next 16 ints)
  if (threadIdx.x < 32) counts[threadIdx.x] = 0;
}

__global__ void cvt_x_kernel(const float* __restrict__ x, _Float16* __restrict__ xb) {
  size_t i = (size_t)(blockIdx.x * 256 + threadIdx.x) * 8;
  float4 a = *(const float4*)(x + i);
  float4 b = *(const float4*)(x + i + 4);
  half8 h;
  h[0] = (_Float16)a.x; h[1] = (_Float16)a.y; h[2] = (_Float16)a.z; h[3] = (_Float16)a.w;
  h[4] = (_Float16)b.x; h[5] = (_Float16)b.y; h[6] = (_Float16)b.z; h[7] = (_Float16)b.w;
  *(half8*)(xb + i) = h;
}

// one wave per token: fp32 routing (discrete decisions must match reference)
__global__ void gate_kernel(const float* __restrict__ x, const float* __restrict__ gw,
                            const float* __restrict__ bias, int* __restrict__ toke,
                            float* __restrict__ tokg, int* __restrict__ counts) {
  const int wid  = blockIdx.x * 4 + (threadIdx.x >> 6); // token id
  const int lane = threadIdx.x & 63;
  const float4* xv = (const float4*)(x + (size_t)wid * HDIM);
  const float4* gv = (const float4*)gw;
  float acc[NEXP];
#pragma unroll
  for (int e = 0; e < NEXP; ++e) acc[e] = 0.f;
#pragma unroll
  for (int i = 0; i < 8; ++i) {
    float4 xq = xv[lane + 64 * i];
#pragma unroll
    for (int e = 0; e < NEXP; ++e) {
      float4 gq = gv[e * 512 + lane + 64 * i];
      acc[e] += xq.x * gq.x + xq.y * gq.y + xq.z * gq.z + xq.w * gq.w;
    }
  }
#pragma unroll
  for (int e = 0; e < NEXP; ++e) {
    float v = acc[e];
    for (int off = 32; off; off >>= 1) v += __shfl_xor(v, off);
    acc[e] = v;
  }
  if (lane == 0) {
    float s[NEXP], r[NEXP];
#pragma unroll
    for (int e = 0; e < NEXP; ++e) {
      s[e] = 1.f / (1.f + __expf(-acc[e]));
      r[e] = s[e] + bias[e];
    }
    int e0 = 0;
#pragma unroll
    for (int e = 1; e < NEXP; ++e) if (r[e] > r[e0]) e0 = e;
    int e1 = -1;
#pragma unroll
    for (int e = 0; e < NEXP; ++e) if (e != e0 && (e1 < 0 || r[e] > r[e1])) e1 = e;
    float g0 = s[e0], g1 = s[e1];
    float inv = 1.f / (g0 + g1);
    toke[wid * 2]     = e0;
    toke[wid * 2 + 1] = e1;
    tokg[wid * 2]     = g0 * inv;
    tokg[wid * 2 + 1] = g1 * inv;
    atomicAdd(&counts[e0], 1);
    atomicAdd(&counts[e1], 1);
  }
}

__global__ void offsets_kernel(const int* __restrict__ counts, int* __restrict__ offs) {
  if (threadIdx.x == 0) {
    int o = 0;
    for (int e = 0; e < NEXP; ++e) { offs[e] = o; o += counts[e]; }
  }
}

__global__ void scatter_kernel(const int* __restrict__ toke, const float* __restrict__ tokg,
                               const int* __restrict__ offs, int* __restrict__ fill,
                               int* __restrict__ slott, float* __restrict__ slotg) {
  int t = blockIdx.x * 256 + threadIdx.x;
#pragma unroll
  for (int j = 0; j < 2; ++j) {
    int e = toke[t * 2 + j];
    float g = tokg[t * 2 + j];
    int p = offs[e] + atomicAdd(&fill[e], 1);
    slott[p] = t;
    slotg[p] = g;
  }
}

// ---------------- GEMM kernels ----------------
// Tile: 128x128, BK=64, 256 threads (4 waves as 2x2, each wave 64x64).
// MFMA 16x16x32 f16. LDS rows padded to 72 f16 (2-way bank conflicts only).
// A (f16, from ws), B (fp32 weights, converted to f16 at staging).

// up: computes silu(A·W1^T) * (A·W3^T) -> act (f16)
template <bool GATHER>
__global__ __launch_bounds__(256) void up_kernel(
    const _Float16* __restrict__ xb, const float* __restrict__ w1g,
    const float* __restrict__ w3g, _Float16* __restrict__ act,
    const int* __restrict__ counts, const int* __restrict__ offs,
    const int* __restrict__ slott) {
  int cnt = TDIM, base = 0, e = 0;
  if constexpr (GATHER) {
    e = blockIdx.z;
    cnt = counts[e];
    base = offs[e];
    if ((int)(blockIdx.y * 128) >= cnt) return;
  }
  const int m0 = blockIdx.y * 128, n0 = blockIdx.x * 128;
  const float* __restrict__ W1 = w1g + (size_t)e * FDIM * HDIM;
  const float* __restrict__ W3 = w3g + (size_t)e * FDIM * HDIM;

  __shared__ _Float16 As[128 * 72];
  __shared__ _Float16 B1s[128 * 72];
  __shared__ _Float16 B3s[128 * 72];

  const int tid = threadIdx.x;
  const int lane = tid & 63, wave = tid >> 6;
  const int wm = wave >> 1, wn = wave & 1;
  const int lrow = lane & 15, quad = lane >> 4;

  const _Float16* arow[4];
#pragma unroll
  for (int it = 0; it < 4; ++it) {
    int row = (tid + it * 256) >> 3;
    int m = m0 + row;
    int tok;
    if constexpr (GATHER) tok = slott[base + (m < cnt ? m : cnt - 1)];
    else tok = m;
    arow[it] = xb + (size_t)tok * HDIM;
  }

  floatx4 acc1[4][4] = {};
  floatx4 acc3[4][4] = {};

  for (int k0 = 0; k0 < HDIM; k0 += 64) {
#pragma unroll
    for (int it = 0; it < 4; ++it) {
      int slot = tid + it * 256;
      int row = slot >> 3, kc = slot & 7;
      half8 v = *(const half8*)(arow[it] + k0 + kc * 8);
      *(half8*)&As[row * 72 + kc * 8] = v;
    }
#pragma unroll
    for (int it = 0; it < 8; ++it) {
      int slot = tid + it * 256;
      int row = slot >> 4, c4 = slot & 15;
      const float* p1 = W1 + (size_t)(n0 + row) * HDIM + k0 + c4 * 4;
      const float* p3 = W3 + (size_t)(n0 + row) * HDIM + k0 + c4 * 4;
      float4 f1 = *(const float4*)p1;
      float4 f3 = *(const float4*)p3;
      half4 h1, h3;
      h1[0] = (_Float16)f1.x; h1[1] = (_Float16)f1.y; h1[2] = (_Float16)f1.z; h1[3] = (_Float16)f1.w;
      h3[0] = (_Float16)f3.x; h3[1] = (_Float16)f3.y; h3[2] = (_Float16)f3.z; h3[3] = (_Float16)f3.w;
      *(half4*)&B1s[row * 72 + c4 * 4] = h1;
      *(half4*)&B3s[row * 72 + c4 * 4] = h3;
    }
    __syncthreads();
#pragma unroll
    for (int kk = 0; kk < 64; kk += 32) {
      half8 af[4], b1f[4], b3f[4];
#pragma unroll
      for (int i = 0; i < 4; ++i)
        af[i] = *(const half8*)&As[(wm * 64 + i * 16 + lrow) * 72 + kk + quad * 8];
#pragma unroll
      for (int i = 0; i < 4; ++i) {
        b1f[i] = *(const half8*)&B1s[(wn * 64 + i * 16 + lrow) * 72 + kk + quad * 8];
        b3f[i] = *(const half8*)&B3s[(wn * 64 + i * 16 + lrow) * 72 + kk + quad * 8];
      }
#pragma unroll
      for (int ms = 0; ms < 4; ++ms)
#pragma unroll
        for (int ns = 0; ns < 4; ++ns) {
          acc1[ms][ns] = __builtin_amdgcn_mfma_f32_16x16x32_f16(af[ms], b1f[ns], acc1[ms][ns], 0, 0, 0);
          acc3[ms][ns] = __builtin_amdgcn_mfma_f32_16x16x32_f16(af[ms], b3f[ns], acc3[ms][ns], 0, 0, 0);
        }
    }
    __syncthreads();
  }

  // epilogue: silu(h1)*h3 (C/D layout: col=lane&15, row=quad*4+reg)
#pragma unroll
  for (int ms = 0; ms < 4; ++ms)
#pragma unroll
    for (int ns = 0; ns < 4; ++ns)
#pragma unroll
      for (int r = 0; r < 4; ++r) {
        float h1 = acc1[ms][ns][r];
        float h3 = acc3[ms][ns][r];
        float a = h1 / (1.f + __expf(-h1)) * h3;
        int rl = wm * 64 + ms * 16 + quad * 4 + r;
        int f = n0 + wn * 64 + ns * 16 + lrow;
        int m = m0 + rl;
        if constexpr (GATHER) {
          if (m < cnt) act[(size_t)(base + m) * FDIM + f] = (_Float16)a;
        } else {
          act[(size_t)m * FDIM + f] = (_Float16)a;
        }
      }
}

// down: A (f16 act) @ W2^T; shared -> plain store, gather -> g-scaled atomicAdd
template <bool GATHER>
__global__ __launch_bounds__(256) void down_kernel(
    const _Float16* __restrict__ act, const float* __restrict__ w2g,
    float* __restrict__ out, const int* __restrict__ counts,
    const int* __restrict__ offs, const int* __restrict__ slott,
    const float* __restrict__ slotg) {
  int cnt = TDIM, base = 0, e = 0;
  if constexpr (GATHER) {
    e = blockIdx.z;
    cnt = counts[e];
    base = offs[e];
    if ((int)(blockIdx.y * 128) >= cnt) return;
  }
  const int m0 = blockIdx.y * 128, n0 = blockIdx.x * 128;
  const float* __restrict__ W = w2g + (size_t)e * HDIM * FDIM;

  __shared__ _Float16 As[128 * 72];
  __shared__ _Float16 Bs[128 * 72];

  const int tid = threadIdx.x;
  const int lane = tid & 63, wave = tid >> 6;
  const int wm = wave >> 1, wn = wave & 1;
  const int lrow = lane & 15, quad = lane >> 4;

  const _Float16* arow[4];
#pragma unroll
  for (int it = 0; it < 4; ++it) {
    int row = (tid + it * 256) >> 3;
    int m = m0 + row;
    int src;
    if constexpr (GATHER) src = base + (m < cnt ? m : cnt - 1);
    else src = m;
    arow[it] = act + (size_t)src * FDIM;
  }

  floatx4 acc[4][4] = {};

  for (int k0 = 0; k0 < FDIM; k0 += 64) {
#pragma unroll
    for (int it = 0; it < 4; ++it) {
      int slot = tid + it * 256;
      int row = slot >> 3, kc = slot & 7;
      half8 v = *(const half8*)(arow[it] + k0 + kc * 8);
      *(half8*)&As[row * 72 + kc * 8] = v;
    }
#pragma unroll
    for (int it = 0; it < 8; ++it) {
      int slot = tid + it * 256;
      int row = slot >> 4, c4 = slot & 15;
      const float* p = W + (size_t)(n0 + row) * FDIM + k0 + c4 * 4;
      float4 f = *(const float4*)p;
      half4 h;
      h[0] = (_Float16)f.x; h[1] = (_Float16)f.y; h[2] = (_Float16)f.z; h[3] = (_Float16)f.w;
      *(half4*)&Bs[row * 72 + c4 * 4] = h;
    }
    __syncthreads();
#pragma unroll
    for (int kk = 0; kk < 64; kk += 32) {
      half8 af[4], bf[4];
#pragma unroll
      for (int i = 0; i < 4; ++i)
        af[i] = *(const half8*)&As[(wm * 64 + i * 16 + lrow) * 72 + kk + quad * 8];
#pragma unroll
      for (int i = 0; i < 4; ++i)
        bf[i] = *(const half8*)&Bs[(wn * 64 + i * 16 + lrow) * 72 + kk + quad * 8];
#pragma unroll
      for (int ms = 0; ms < 4; ++ms)
#pragma unroll
        for (int ns = 0; ns < 4; ++ns)
          acc[ms][ns] = __builtin_amdgcn_mfma_f32_16x16x32_f16(af[ms], bf[ns], acc[ms][ns], 0, 0, 0);
    }
    __syncthreads();
  }

#pragma unroll
  for (int ms = 0; ms < 4; ++ms)
#pragma unroll
    for (int ns = 0; ns < 4; ++ns)
#pragma unroll
      for (int r = 0; r < 4; ++r) {
        float v = acc[ms][ns][r];
        int rl = wm * 64 + ms * 16 + quad * 4 + r;
        int h = n0 + wn * 64 + ns * 16 + lrow;
        int m = m0 + rl;
        if constexpr (GATHER) {
          if (m < cnt) {
            int slot = base + m;
            atomicAdd(&out[(size_t)slott[slot] * HDIM + h], v * slotg[slot]);
          }
        } else {
          out[(size_t)m * HDIM + h] = v;
        }
      }
}

// ---------------- launcher ----------------

extern "C" void kernel_launch(void* const* d_in, const int* in_sizes, int n_in,
                              void* d_out, int out_size, void* d_ws, size_t ws_size,
                              hipStream_t stream) {
  const float* x    = (const float*)d_in[0];
  const float* gw   = (const float*)d_in[1];
  const float* bias = (const float*)d_in[2];
  const float* ws1  = (const float*)d_in[3];
  const float* ws2  = (const float*)d_in[4];
  const float* ws3  = (const float*)d_in[5];
  const float* we1  = (const float*)d_in[6];
  const float* we2  = (const float*)d_in[7];
  const float* we3  = (const float*)d_in[8];
  float* out = (float*)d_out;

  char* ws = (char*)d_ws;
  _Float16* xb   = (_Float16*)(ws + WS_XB);
  _Float16* acts = (_Float16*)(ws + WS_ACT_S);
  _Float16* actr = (_Float16*)(ws + WS_ACT_R);
  int*   toke  = (int*)(ws + WS_TOKE);
  float* tokg  = (float*)(ws + WS_TOKG);
  int*   slott = (int*)(ws + WS_SLOTT);
  float* slotg = (float*)(ws + WS_SLOTG);
  int* counts  = (int*)(ws + WS_COUNTS);
  int* fill    = (int*)(ws + WS_FILL);
  int* offs    = (int*)(ws + WS_OFFS);

  hipLaunchKernelGGL(zero_meta_kernel, dim3(1), dim3(64), 0, stream, counts);
  hipLaunchKernelGGL(cvt_x_kernel, dim3(4096), dim3(256), 0, stream, x, xb);
  hipLaunchKernelGGL(gate_kernel, dim3(1024), dim3(256), 0, stream, x, gw, bias, toke, tokg, counts);
  hipLaunchKernelGGL(offsets_kernel, dim3(1), dim3(64), 0, stream, counts, offs);
  hipLaunchKernelGGL(scatter_kernel, dim3(16), dim3(256), 0, stream, toke, tokg, offs, fill, slott, slotg);

  // shared expert up (silu fused), then routed up
  hipLaunchKernelGGL((up_kernel<false>), dim3(FDIM / 128, TDIM / 128, 1), dim3(256), 0, stream,
                     xb, ws1, ws3, acts, nullptr, nullptr, nullptr);
  hipLaunchKernelGGL((up_kernel<true>), dim3(FDIM / 128, TDIM / 128, NEXP), dim3(256), 0, stream,
                     xb, we1, we3, actr, counts, offs, slott);

  // shared down writes out fully; routed down atomically accumulates after it
  hipLaunchKernelGGL((down_kernel<false>), dim3(HDIM / 128, TDIM / 128, 1), dim3(256), 0, stream,
                     acts, ws2, out, nullptr, nullptr, nullptr, nullptr);
  hipLaunchKernelGGL((down_kernel<true>), dim3(HDIM / 128, TDIM / 128, NEXP), dim3(256), 0, stream,
                     actr, we2, out, counts, offs, slott, slotg);
}

// Round 2
// 1055.949 us; speedup vs baseline: 1.0559x; 1.0559x over previous
//
#include <hip/hip_runtime.h>
#include <cstdint>
#include <cstddef>
#include <type_traits>

#define TDIM 4096
#define HDIM 2048
#define FDIM 1408
#define NEXP 8
#define NSLOT (TDIM * 2)

typedef _Float16 half8 __attribute__((ext_vector_type(8)));
typedef _Float16 half4 __attribute__((ext_vector_type(4)));
typedef float floatx4 __attribute__((ext_vector_type(4)));

// ---------------- ws layout (bytes) ----------------
static constexpr size_t ws_align(size_t x) { return (x + 511) & ~(size_t)511; }
static constexpr size_t WS_XB     = 0;                                  // f16 [TDIM][HDIM]
static constexpr size_t WS_ACT_S  = WS_XB    + (size_t)TDIM * HDIM * 2; // f16 [TDIM][FDIM]
static constexpr size_t WS_ACT_R  = WS_ACT_S + (size_t)TDIM * FDIM * 2; // f16 [NSLOT][FDIM]
static constexpr size_t WS_TOKE   = WS_ACT_R + (size_t)NSLOT * FDIM * 2;// int  [TDIM][2]
static constexpr size_t WS_TOKG   = WS_TOKE  + (size_t)TDIM * 2 * 4;    // f32  [TDIM][2]
static constexpr size_t WS_SLOTT  = WS_TOKG  + (size_t)TDIM * 2 * 4;    // int  [NSLOT]
static constexpr size_t WS_SLOTG  = WS_SLOTT + (size_t)NSLOT * 4;       // f32  [NSLOT]
static constexpr size_t WS_COUNTS = WS_SLOTG + (size_t)NSLOT * 4;       // int  [NEXP] (64B slot)
static constexpr size_t WS_FILL   = WS_COUNTS + 64;                     // int  [NEXP] (64B slot)
static constexpr size_t WS_OFFS   = WS_FILL   + 64;                     // int  [NEXP]
// f16 weight cache (all experts fit in 256MB L3 once halved: 138MB routed + 17MB shared)
static constexpr size_t WS_WS1H   = ws_align(WS_OFFS + 64);
static constexpr size_t WS_WS3H   = WS_WS1H + (size_t)FDIM * HDIM * 2;
static constexpr size_t WS_WS2H   = WS_WS3H + (size_t)FDIM * HDIM * 2;
static constexpr size_t WS_WE1H   = WS_WS2H + (size_t)HDIM * FDIM * 2;
static constexpr size_t WS_WE3H   = WS_WE1H + (size_t)NEXP * FDIM * HDIM * 2;
static constexpr size_t WS_WE2H   = WS_WE3H + (size_t)NEXP * FDIM * HDIM * 2;
static constexpr size_t WS_END    = WS_WE2H + (size_t)NEXP * HDIM * FDIM * 2;

// ---------------- small kernels ----------------

__global__ void zero_meta_kernel(int* __restrict__ counts) {
  if (threadIdx.x < 32) counts[threadIdx.x] = 0;
}

// fp32 -> f16, 8 elems/thread
__global__ void cvt_kernel(const float* __restrict__ src, _Float16* __restrict__ dst) {
  size_t i = ((size_t)blockIdx.x * 256 + threadIdx.x) * 8;
  float4 a = *(const float4*)(src + i);
  float4 b = *(const float4*)(src + i + 4);
  half8 h;
  h[0] = (_Float16)a.x; h[1] = (_Float16)a.y; h[2] = (_Float16)a.z; h[3] = (_Float16)a.w;
  h[4] = (_Float16)b.x; h[5] = (_Float16)b.y; h[6] = (_Float16)b.z; h[7] = (_Float16)b.w;
  *(half8*)(dst + i) = h;
}

// one wave per token: fp32 routing (discrete decisions must match reference)
__global__ void gate_kernel(const float* __restrict__ x, const float* __restrict__ gw,
                            const float* __restrict__ bias, int* __restrict__ toke,
                            float* __restrict__ tokg, int* __restrict__ counts) {
  const int wid  = blockIdx.x * 4 + (threadIdx.x >> 6); // token id
  const int lane = threadIdx.x & 63;
  const float4* xv = (const float4*)(x + (size_t)wid * HDIM);
  const float4* gv = (const float4*)gw;
  float acc[NEXP];
#pragma unroll
  for (int e = 0; e < NEXP; ++e) acc[e] = 0.f;
#pragma unroll
  for (int i = 0; i < 8; ++i) {
    float4 xq = xv[lane + 64 * i];
#pragma unroll
    for (int e = 0; e < NEXP; ++e) {
      float4 gq = gv[e * 512 + lane + 64 * i];
      acc[e] += xq.x * gq.x + xq.y * gq.y + xq.z * gq.z + xq.w * gq.w;
    }
  }
#pragma unroll
  for (int e = 0; e < NEXP; ++e) {
    float v = acc[e];
    for (int off = 32; off; off >>= 1) v += __shfl_xor(v, off);
    acc[e] = v;
  }
  if (lane == 0) {
    float s[NEXP], r[NEXP];
#pragma unroll
    for (int e = 0; e < NEXP; ++e) {
      s[e] = 1.f / (1.f + __expf(-acc[e]));
      r[e] = s[e] + bias[e];
    }
    int e0 = 0;
#pragma unroll
    for (int e = 1; e < NEXP; ++e) if (r[e] > r[e0]) e0 = e;
    int e1 = -1;
#pragma unroll
    for (int e = 0; e < NEXP; ++e) if (e != e0 && (e1 < 0 || r[e] > r[e1])) e1 = e;
    float g0 = s[e0], g1 = s[e1];
    float inv = 1.f / (g0 + g1);
    toke[wid * 2]     = e0;
    toke[wid * 2 + 1] = e1;
    tokg[wid * 2]     = g0 * inv;
    tokg[wid * 2 + 1] = g1 * inv;
    atomicAdd(&counts[e0], 1);
    atomicAdd(&counts[e1], 1);
  }
}

__global__ void offsets_kernel(const int* __restrict__ counts, int* __restrict__ offs) {
  if (threadIdx.x == 0) {
    int o = 0;
    for (int e = 0; e < NEXP; ++e) { offs[e] = o; o += counts[e]; }
  }
}

__global__ void scatter_kernel(const int* __restrict__ toke, const float* __restrict__ tokg,
                               const int* __restrict__ offs, int* __restrict__ fill,
                               int* __restrict__ slott, float* __restrict__ slotg) {
  int t = blockIdx.x * 256 + threadIdx.x;
#pragma unroll
  for (int j = 0; j < 2; ++j) {
    int e = toke[t * 2 + j];
    float g = tokg[t * 2 + j];
    int p = offs[e] + atomicAdd(&fill[e], 1);
    slott[p] = t;
    slotg[p] = g;
  }
}

// ---------------- GEMM kernels ----------------
// Tile: 128x128, BK=64, 256 threads (4 waves as 2x2, each wave 64x64).
// MFMA 16x16x32 f16. LDS rows padded to 72 f16 (2-way bank conflicts = free).
// WT = _Float16 (pre-converted cache in ws) or float (fallback, converted at staging).

template <typename WT>
__device__ inline void stage_b(const WT* __restrict__ W, _Float16* __restrict__ Bs,
                               int tid, int n0, int k0, int K) {
  if constexpr (std::is_same<WT, _Float16>::value) {
#pragma unroll
    for (int it = 0; it < 4; ++it) {
      int slot = tid + it * 256;
      int row = slot >> 3, kc = slot & 7;
      *(half8*)&Bs[row * 72 + kc * 8] =
          *(const half8*)(W + (size_t)(n0 + row) * K + k0 + kc * 8);
    }
  } else {
#pragma unroll
    for (int it = 0; it < 8; ++it) {
      int slot = tid + it * 256;
      int row = slot >> 4, c4 = slot & 15;
      float4 f = *(const float4*)(W + (size_t)(n0 + row) * K + k0 + c4 * 4);
      half4 h;
      h[0] = (_Float16)f.x; h[1] = (_Float16)f.y; h[2] = (_Float16)f.z; h[3] = (_Float16)f.w;
      *(half4*)&Bs[row * 72 + c4 * 4] = h;
    }
  }
}

// up: computes silu(A·W1^T) * (A·W3^T) -> act (f16)
template <bool GATHER, typename WT>
__global__ __launch_bounds__(256) void up_kernel(
    const _Float16* __restrict__ xb, const WT* __restrict__ w1g,
    const WT* __restrict__ w3g, _Float16* __restrict__ act,
    const int* __restrict__ counts, const int* __restrict__ offs,
    const int* __restrict__ slott) {
  int cnt = TDIM, base = 0, e = 0;
  if constexpr (GATHER) {
    e = blockIdx.z;
    cnt = counts[e];
    base = offs[e];
    if ((int)(blockIdx.y * 128) >= cnt) return;
  }
  const int m0 = blockIdx.y * 128, n0 = blockIdx.x * 128;
  const WT* __restrict__ W1 = w1g + (size_t)e * FDIM * HDIM;
  const WT* __restrict__ W3 = w3g + (size_t)e * FDIM * HDIM;

  __shared__ _Float16 As[128 * 72];
  __shared__ _Float16 B1s[128 * 72];
  __shared__ _Float16 B3s[128 * 72];

  const int tid = threadIdx.x;
  const int lane = tid & 63, wave = tid >> 6;
  const int wm = wave >> 1, wn = wave & 1;
  const int lrow = lane & 15, quad = lane >> 4;

  const _Float16* arow[4];
#pragma unroll
  for (int it = 0; it < 4; ++it) {
    int row = (tid + it * 256) >> 3;
    int m = m0 + row;
    int tok;
    if constexpr (GATHER) {
      int idx = base + (m < cnt ? m : (cnt > 0 ? cnt - 1 : 0));
      tok = slott[idx] & (TDIM - 1);  // clamp for safety (empty-expert edge)
    } else tok = m;
    arow[it] = xb + (size_t)tok * HDIM;
  }

  floatx4 acc1[4][4] = {};
  floatx4 acc3[4][4] = {};

  for (int k0 = 0; k0 < HDIM; k0 += 64) {
#pragma unroll
    for (int it = 0; it < 4; ++it) {
      int slot = tid + it * 256;
      int row = slot >> 3, kc = slot & 7;
      *(half8*)&As[row * 72 + kc * 8] = *(const half8*)(arow[it] + k0 + kc * 8);
    }
    stage_b(W1, B1s, tid, n0, k0, HDIM);
    stage_b(W3, B3s, tid, n0, k0, HDIM);
    __syncthreads();
#pragma unroll
    for (int kk = 0; kk < 64; kk += 32) {
      half8 af[4], b1f[4], b3f[4];
#pragma unroll
      for (int i = 0; i < 4; ++i)
        af[i] = *(const half8*)&As[(wm * 64 + i * 16 + lrow) * 72 + kk + quad * 8];
#pragma unroll
      for (int i = 0; i < 4; ++i) {
        b1f[i] = *(const half8*)&B1s[(wn * 64 + i * 16 + lrow) * 72 + kk + quad * 8];
        b3f[i] = *(const half8*)&B3s[(wn * 64 + i * 16 + lrow) * 72 + kk + quad * 8];
      }
#pragma unroll
      for (int ms = 0; ms < 4; ++ms)
#pragma unroll
        for (int ns = 0; ns < 4; ++ns) {
          acc1[ms][ns] = __builtin_amdgcn_mfma_f32_16x16x32_f16(af[ms], b1f[ns], acc1[ms][ns], 0, 0, 0);
          acc3[ms][ns] = __builtin_amdgcn_mfma_f32_16x16x32_f16(af[ms], b3f[ns], acc3[ms][ns], 0, 0, 0);
        }
    }
    __syncthreads();
  }

  // epilogue: silu(h1)*h3 (C/D layout: col=lane&15, row=quad*4+reg)
#pragma unroll
  for (int ms = 0; ms < 4; ++ms)
#pragma unroll
    for (int ns = 0; ns < 4; ++ns)
#pragma unroll
      for (int r = 0; r < 4; ++r) {
        float h1 = acc1[ms][ns][r];
        float h3 = acc3[ms][ns][r];
        float a = h1 / (1.f + __expf(-h1)) * h3;
        int rl = wm * 64 + ms * 16 + quad * 4 + r;
        int f = n0 + wn * 64 + ns * 16 + lrow;
        int m = m0 + rl;
        if constexpr (GATHER) {
          if (m < cnt) act[(size_t)(base + m) * FDIM + f] = (_Float16)a;
        } else {
          act[(size_t)m * FDIM + f] = (_Float16)a;
        }
      }
}

// down: A (f16 act) @ W2^T; shared -> plain store, gather -> g-scaled atomicAdd
template <bool GATHER, typename WT>
__global__ __launch_bounds__(256) void down_kernel(
    const _Float16* __restrict__ act, const WT* __restrict__ w2g,
    float* __restrict__ out, const int* __restrict__ counts,
    const int* __restrict__ offs, const int* __restrict__ slott,
    const float* __restrict__ slotg) {
  int cnt = TDIM, base = 0, e = 0;
  if constexpr (GATHER) {
    e = blockIdx.z;
    cnt = counts[e];
    base = offs[e];
    if ((int)(blockIdx.y * 128) >= cnt) return;
  }
  const int m0 = blockIdx.y * 128, n0 = blockIdx.x * 128;
  const WT* __restrict__ W = w2g + (size_t)e * HDIM * FDIM;

  __shared__ _Float16 As[128 * 72];
  __shared__ _Float16 Bs[128 * 72];

  const int tid = threadIdx.x;
  const int lane = tid & 63, wave = tid >> 6;
  const int wm = wave >> 1, wn = wave & 1;
  const int lrow = lane & 15, quad = lane >> 4;

  const _Float16* arow[4];
#pragma unroll
  for (int it = 0; it < 4; ++it) {
    int row = (tid + it * 256) >> 3;
    int m = m0 + row;
    int src;
    if constexpr (GATHER) src = base + (m < cnt ? m : (cnt > 0 ? cnt - 1 : 0));
    else src = m;
    arow[it] = act + (size_t)src * FDIM;
  }

  floatx4 acc[4][4] = {};

  for (int k0 = 0; k0 < FDIM; k0 += 64) {
#pragma unroll
    for (int it = 0; it < 4; ++it) {
      int slot = tid + it * 256;
      int row = slot >> 3, kc = slot & 7;
      *(half8*)&As[row * 72 + kc * 8] = *(const half8*)(arow[it] + k0 + kc * 8);
    }
    stage_b(W, Bs, tid, n0, k0, FDIM);
    __syncthreads();
#pragma unroll
    for (int kk = 0; kk < 64; kk += 32) {
      half8 af[4], bf[4];
#pragma unroll
      for (int i = 0; i < 4; ++i)
        af[i] = *(const half8*)&As[(wm * 64 + i * 16 + lrow) * 72 + kk + quad * 8];
#pragma unroll
      for (int i = 0; i < 4; ++i)
        bf[i] = *(const half8*)&Bs[(wn * 64 + i * 16 + lrow) * 72 + kk + quad * 8];
#pragma unroll
      for (int ms = 0; ms < 4; ++ms)
#pragma unroll
        for (int ns = 0; ns < 4; ++ns)
          acc[ms][ns] = __builtin_amdgcn_mfma_f32_16x16x32_f16(af[ms], bf[ns], acc[ms][ns], 0, 0, 0);
    }
    __syncthreads();
  }

#pragma unroll
  for (int ms = 0; ms < 4; ++ms)
#pragma unroll
    for (int ns = 0; ns < 4; ++ns)
#pragma unroll
      for (int r = 0; r < 4; ++r) {
        float v = acc[ms][ns][r];
        int rl = wm * 64 + ms * 16 + quad * 4 + r;
        int h = n0 + wn * 64 + ns * 16 + lrow;
        int m = m0 + rl;
        if constexpr (GATHER) {
          if (m < cnt) {
            int slot = base + m;
            atomicAdd(&out[(size_t)slott[slot] * HDIM + h], v * slotg[slot]);
          }
        } else {
          out[(size_t)m * HDIM + h] = v;
        }
      }
}

// ---------------- launcher ----------------

extern "C" void kernel_launch(void* const* d_in, const int* in_sizes, int n_in,
                              void* d_out, int out_size, void* d_ws, size_t ws_size,
                              hipStream_t stream) {
  const float* x    = (const float*)d_in[0];
  const float* gw   = (const float*)d_in[1];
  const float* bias = (const float*)d_in[2];
  const float* ws1  = (const float*)d_in[3];
  const float* ws2  = (const float*)d_in[4];
  const float* ws3  = (const float*)d_in[5];
  const float* we1  = (const float*)d_in[6];
  const float* we2  = (const float*)d_in[7];
  const float* we3  = (const float*)d_in[8];
  float* out = (float*)d_out;

  char* ws = (char*)d_ws;
  _Float16* xb   = (_Float16*)(ws + WS_XB);
  _Float16* acts = (_Float16*)(ws + WS_ACT_S);
  _Float16* actr = (_Float16*)(ws + WS_ACT_R);
  int*   toke  = (int*)(ws + WS_TOKE);
  float* tokg  = (float*)(ws + WS_TOKG);
  int*   slott = (int*)(ws + WS_SLOTT);
  float* slotg = (float*)(ws + WS_SLOTG);
  int* counts  = (int*)(ws + WS_COUNTS);
  int* fill    = (int*)(ws + WS_FILL);
  int* offs    = (int*)(ws + WS_OFFS);

  hipLaunchKernelGGL(zero_meta_kernel, dim3(1), dim3(64), 0, stream, counts);
  hipLaunchKernelGGL(cvt_kernel, dim3(4096), dim3(256), 0, stream, x, xb);
  hipLaunchKernelGGL(gate_kernel, dim3(1024), dim3(256), 0, stream, x, gw, bias, toke, tokg, counts);
  hipLaunchKernelGGL(offsets_kernel, dim3(1), dim3(64), 0, stream, counts, offs);
  hipLaunchKernelGGL(scatter_kernel, dim3(16), dim3(256), 0, stream, toke, tokg, offs, fill, slott, slotg);

  const bool f16w = ws_size >= WS_END;  // constant across calls -> graph-safe
  if (f16w) {
    _Float16* ws1h = (_Float16*)(ws + WS_WS1H);
    _Float16* ws3h = (_Float16*)(ws + WS_WS3H);
    _Float16* ws2h = (_Float16*)(ws + WS_WS2H);
    _Float16* we1h = (_Float16*)(ws + WS_WE1H);
    _Float16* we3h = (_Float16*)(ws + WS_WE3H);
    _Float16* we2h = (_Float16*)(ws + WS_WE2H);
    constexpr int GS = (FDIM * HDIM) / 2048;           // 1408
    constexpr int GR = (NEXP * FDIM * HDIM) / 2048;    // 11264
    hipLaunchKernelGGL(cvt_kernel, dim3(GS), dim3(256), 0, stream, ws1, ws1h);
    hipLaunchKernelGGL(cvt_kernel, dim3(GS), dim3(256), 0, stream, ws3, ws3h);
    hipLaunchKernelGGL(cvt_kernel, dim3(GS), dim3(256), 0, stream, ws2, ws2h);
    hipLaunchKernelGGL(cvt_kernel, dim3(GR), dim3(256), 0, stream, we1, we1h);
    hipLaunchKernelGGL(cvt_kernel, dim3(GR), dim3(256), 0, stream, we3, we3h);
    hipLaunchKernelGGL(cvt_kernel, dim3(GR), dim3(256), 0, stream, we2, we2h);

    hipLaunchKernelGGL((up_kernel<false, _Float16>), dim3(FDIM / 128, TDIM / 128, 1), dim3(256), 0, stream,
                       xb, ws1h, ws3h, acts, nullptr, nullptr, nullptr);
    hipLaunchKernelGGL((up_kernel<true, _Float16>), dim3(FDIM / 128, TDIM / 128, NEXP), dim3(256), 0, stream,
                       xb, we1h, we3h, actr, counts, offs, slott);
    hipLaunchKernelGGL((down_kernel<false, _Float16>), dim3(HDIM / 128, TDIM / 128, 1), dim3(256), 0, stream,
                       acts, ws2h, out, nullptr, nullptr, nullptr, nullptr);
    hipLaunchKernelGGL((down_kernel<true, _Float16>), dim3(HDIM / 128, TDIM / 128, NEXP), dim3(256), 0, stream,
                       actr, we2h, out, counts, offs, slott, slotg);
  } else {
    hipLaunchKernelGGL((up_kernel<false, float>), dim3(FDIM / 128, TDIM / 128, 1), dim3(256), 0, stream,
                       xb, ws1, ws3, acts, nullptr, nullptr, nullptr);
    hipLaunchKernelGGL((up_kernel<true, float>), dim3(FDIM / 128, TDIM / 128, NEXP), dim3(256), 0, stream,
                       xb, we1, we3, actr, counts, offs, slott);
    hipLaunchKernelGGL((down_kernel<false, float>), dim3(HDIM / 128, TDIM / 128, 1), dim3(256), 0, stream,
                       acts, ws2, out, nullptr, nullptr, nullptr, nullptr);
    hipLaunchKernelGGL((down_kernel<true, float>), dim3(HDIM / 128, TDIM / 128, NEXP), dim3(256), 0, stream,
                       actr, we2, out, counts, offs, slott, slotg);
  }
}

// Round 3
// 1032.892 us; speedup vs baseline: 1.0795x; 1.0223x over previous
//
#include <hip/hip_runtime.h>
#include <cstdint>
#include <cstddef>

#define TDIM 4096
#define HDIM 2048
#define FDIM 1408
#define NEXP 8
#define NSLOT (TDIM * 2)

typedef _Float16 half8 __attribute__((ext_vector_type(8)));
typedef float floatx4 __attribute__((ext_vector_type(4)));

#define AS1 __attribute__((address_space(1)))
#define AS3 __attribute__((address_space(3)))

// async global->LDS, 16B per lane; lds dst must be wave-uniform base (lane scatters +lane*16B)
__device__ __forceinline__ void g2l16(const _Float16* g, _Float16* l) {
  __builtin_amdgcn_global_load_lds((const AS1 unsigned*)g, (AS3 unsigned*)l, 16, 0, 0);
}

// ---------------- ws layout (bytes) ----------------
static constexpr size_t ws_align(size_t x) { return (x + 511) & ~(size_t)511; }
static constexpr size_t WS_XB     = 0;                                  // f16 [TDIM][HDIM]
static constexpr size_t WS_ACT_S  = WS_XB    + (size_t)TDIM * HDIM * 2; // f16 [TDIM][FDIM]
static constexpr size_t WS_ACT_R  = WS_ACT_S + (size_t)TDIM * FDIM * 2; // f16 [NSLOT][FDIM]
static constexpr size_t WS_TOKE   = WS_ACT_R + (size_t)NSLOT * FDIM * 2;// int  [TDIM][2]
static constexpr size_t WS_TOKG   = WS_TOKE  + (size_t)TDIM * 2 * 4;    // f32  [TDIM][2]
static constexpr size_t WS_SLOTT  = WS_TOKG  + (size_t)TDIM * 2 * 4;    // int  [NSLOT]
static constexpr size_t WS_SLOTG  = WS_SLOTT + (size_t)NSLOT * 4;       // f32  [NSLOT]
static constexpr size_t WS_COUNTS = WS_SLOTG + (size_t)NSLOT * 4;       // int  [NEXP] (64B slot)
static constexpr size_t WS_FILL   = WS_COUNTS + 64;                     // int  [NEXP] (64B slot)
static constexpr size_t WS_OFFS   = WS_FILL   + 64;                     // int  [NEXP]
static constexpr size_t WS_WS1H   = ws_align(WS_OFFS + 64);
static constexpr size_t WS_WS3H   = WS_WS1H + (size_t)FDIM * HDIM * 2;
static constexpr size_t WS_WS2H   = WS_WS3H + (size_t)FDIM * HDIM * 2;
static constexpr size_t WS_WE1H   = WS_WS2H + (size_t)HDIM * FDIM * 2;
static constexpr size_t WS_WE3H   = WS_WE1H + (size_t)NEXP * FDIM * HDIM * 2;
static constexpr size_t WS_WE2H   = WS_WE3H + (size_t)NEXP * FDIM * HDIM * 2;
static constexpr size_t WS_END    = WS_WE2H + (size_t)NEXP * HDIM * FDIM * 2;

// ---------------- small kernels ----------------

__global__ void zero_meta_kernel(int* __restrict__ counts) {
  if (threadIdx.x < 32) counts[threadIdx.x] = 0;
}

// fp32 -> f16, 8 elems/thread
__global__ void cvt_kernel(const float* __restrict__ src, _Float16* __restrict__ dst) {
  size_t i = ((size_t)blockIdx.x * 256 + threadIdx.x) * 8;
  float4 a = *(const float4*)(src + i);
  float4 b = *(const float4*)(src + i + 4);
  half8 h;
  h[0] = (_Float16)a.x; h[1] = (_Float16)a.y; h[2] = (_Float16)a.z; h[3] = (_Float16)a.w;
  h[4] = (_Float16)b.x; h[5] = (_Float16)b.y; h[6] = (_Float16)b.z; h[7] = (_Float16)b.w;
  *(half8*)(dst + i) = h;
}

// one wave per token: fp32 routing (discrete decisions must match reference)
__global__ void gate_kernel(const float* __restrict__ x, const float* __restrict__ gw,
                            const float* __restrict__ bias, int* __restrict__ toke,
                            float* __restrict__ tokg, int* __restrict__ counts) {
  const int wid  = blockIdx.x * 4 + (threadIdx.x >> 6);
  const int lane = threadIdx.x & 63;
  const float4* xv = (const float4*)(x + (size_t)wid * HDIM);
  const float4* gv = (const float4*)gw;
  float acc[NEXP];
#pragma unroll
  for (int e = 0; e < NEXP; ++e) acc[e] = 0.f;
#pragma unroll
  for (int i = 0; i < 8; ++i) {
    float4 xq = xv[lane + 64 * i];
#pragma unroll
    for (int e = 0; e < NEXP; ++e) {
      float4 gq = gv[e * 512 + lane + 64 * i];
      acc[e] += xq.x * gq.x + xq.y * gq.y + xq.z * gq.z + xq.w * gq.w;
    }
  }
#pragma unroll
  for (int e = 0; e < NEXP; ++e) {
    float v = acc[e];
    for (int off = 32; off; off >>= 1) v += __shfl_xor(v, off);
    acc[e] = v;
  }
  if (lane == 0) {
    float s[NEXP], r[NEXP];
#pragma unroll
    for (int e = 0; e < NEXP; ++e) {
      s[e] = 1.f / (1.f + __expf(-acc[e]));
      r[e] = s[e] + bias[e];
    }
    int e0 = 0;
#pragma unroll
    for (int e = 1; e < NEXP; ++e) if (r[e] > r[e0]) e0 = e;
    int e1 = -1;
#pragma unroll
    for (int e = 0; e < NEXP; ++e) if (e != e0 && (e1 < 0 || r[e] > r[e1])) e1 = e;
    float g0 = s[e0], g1 = s[e1];
    float inv = 1.f / (g0 + g1);
    toke[wid * 2]     = e0;
    toke[wid * 2 + 1] = e1;
    tokg[wid * 2]     = g0 * inv;
    tokg[wid * 2 + 1] = g1 * inv;
    atomicAdd(&counts[e0], 1);
    atomicAdd(&counts[e1], 1);
  }
}

__global__ void offsets_kernel(const int* __restrict__ counts, int* __restrict__ offs) {
  if (threadIdx.x == 0) {
    int o = 0;
    for (int e = 0; e < NEXP; ++e) { offs[e] = o; o += counts[e]; }
  }
}

__global__ void scatter_kernel(const int* __restrict__ toke, const float* __restrict__ tokg,
                               const int* __restrict__ offs, int* __restrict__ fill,
                               int* __restrict__ slott, float* __restrict__ slotg) {
  int t = blockIdx.x * 256 + threadIdx.x;
#pragma unroll
  for (int j = 0; j < 2; ++j) {
    int e = toke[t * 2 + j];
    float g = tokg[t * 2 + j];
    int p = offs[e] + atomicAdd(&fill[e], 1);
    slott[p] = t;
    slotg[p] = g;
  }
}

// ---------------- GEMM kernels ----------------
// 128x128 tile, BK=64, 256 thr (4 waves, 2x2 of 64x64), MFMA 16x16x32 f16.
// LDS unpadded [128][64] f16, staged via global_load_lds 16B/lane.
// XOR column swizzle applied at the GLOBAL source: LDS[row][cb] = G[row][cb^(row&7)],
// readback col' = col ^ (row&7) -> ds_read_b128 spreads over all bank groups (2-way only).

// up: silu(A.W1^T) * (A.W3^T) -> act (f16)
template <bool GATHER>
__global__ __launch_bounds__(256) void up_kernel(
    const _Float16* __restrict__ xb, const _Float16* __restrict__ w1g,
    const _Float16* __restrict__ w3g, _Float16* __restrict__ act,
    const int* __restrict__ counts, const int* __restrict__ offs,
    const int* __restrict__ slott) {
  int cnt = TDIM, base = 0, e = 0;
  if constexpr (GATHER) {
    e = blockIdx.z;
    cnt = counts[e];
    base = offs[e];
    if ((int)(blockIdx.y * 128) >= cnt) return;
  }
  const int m0 = blockIdx.y * 128, n0 = blockIdx.x * 128;
  const _Float16* __restrict__ W1 = w1g + (size_t)e * FDIM * HDIM;
  const _Float16* __restrict__ W3 = w3g + (size_t)e * FDIM * HDIM;

  __shared__ _Float16 As[128 * 64];
  __shared__ _Float16 B1s[128 * 64];
  __shared__ _Float16 B3s[128 * 64];

  const int tid = threadIdx.x, lane = tid & 63, wave = tid >> 6;
  const int wm = wave >> 1, wn = wave & 1;
  const int lrow = lane & 15, quad = lane >> 4;
  const int subrow = lane >> 3, cb = lane & 7;
  const int scb = (cb ^ subrow) * 8;  // swizzled source col offset (halfs); row&7==subrow

  const _Float16 *gA[4], *gB1[4], *gB3[4];
#pragma unroll
  for (int it = 0; it < 4; ++it) {
    int r = (it * 4 + wave) * 8 + subrow;  // tile row this lane stages
    int m = m0 + r;
    int tok;
    if constexpr (GATHER) tok = slott[base + (m < cnt ? m : cnt - 1)];
    else tok = m;
    gA[it]  = xb + (size_t)tok * HDIM + scb;
    gB1[it] = W1 + (size_t)(n0 + r) * HDIM + scb;
    gB3[it] = W3 + (size_t)(n0 + r) * HDIM + scb;
  }

  floatx4 acc1[4][4] = {};
  floatx4 acc3[4][4] = {};
  const int s = lrow & 7;

  for (int k0 = 0; k0 < HDIM; k0 += 64) {
#pragma unroll
    for (int it = 0; it < 4; ++it) {
      const int lb = (it * 4 + wave) * 512;  // 8 rows * 64 halfs
      g2l16(gA[it] + k0,  &As[lb]);
      g2l16(gB1[it] + k0, &B1s[lb]);
      g2l16(gB3[it] + k0, &B3s[lb]);
    }
    __syncthreads();
#pragma unroll
    for (int kk = 0; kk < 64; kk += 32) {
      const int cb0 = (kk >> 3) + quad;
      const int co = (cb0 ^ s) * 8;
      half8 af[4], b1f[4], b3f[4];
#pragma unroll
      for (int i = 0; i < 4; ++i)
        af[i] = *(const half8*)&As[(wm * 64 + i * 16 + lrow) * 64 + co];
#pragma unroll
      for (int i = 0; i < 4; ++i) {
        b1f[i] = *(const half8*)&B1s[(wn * 64 + i * 16 + lrow) * 64 + co];
        b3f[i] = *(const half8*)&B3s[(wn * 64 + i * 16 + lrow) * 64 + co];
      }
#pragma unroll
      for (int ms = 0; ms < 4; ++ms)
#pragma unroll
        for (int ns = 0; ns < 4; ++ns) {
          acc1[ms][ns] = __builtin_amdgcn_mfma_f32_16x16x32_f16(af[ms], b1f[ns], acc1[ms][ns], 0, 0, 0);
          acc3[ms][ns] = __builtin_amdgcn_mfma_f32_16x16x32_f16(af[ms], b3f[ns], acc3[ms][ns], 0, 0, 0);
        }
    }
    __syncthreads();
  }

  // epilogue: silu(h1)*h3 (C/D layout: col=lane&15, row=quad*4+reg)
#pragma unroll
  for (int ms = 0; ms < 4; ++ms)
#pragma unroll
    for (int ns = 0; ns < 4; ++ns)
#pragma unroll
      for (int r = 0; r < 4; ++r) {
        float h1 = acc1[ms][ns][r];
        float h3 = acc3[ms][ns][r];
        float a = h1 / (1.f + __expf(-h1)) * h3;
        int rl = wm * 64 + ms * 16 + quad * 4 + r;
        int f = n0 + wn * 64 + ns * 16 + lrow;
        int m = m0 + rl;
        if constexpr (GATHER) {
          if (m < cnt) act[(size_t)(base + m) * FDIM + f] = (_Float16)a;
        } else {
          act[(size_t)m * FDIM + f] = (_Float16)a;
        }
      }
}

// down: A (f16 act) @ W2^T; shared -> plain store, gather -> g-scaled atomicAdd
template <bool GATHER>
__global__ __launch_bounds__(256) void down_kernel(
    const _Float16* __restrict__ act, const _Float16* __restrict__ w2g,
    float* __restrict__ out, const int* __restrict__ counts,
    const int* __restrict__ offs, const int* __restrict__ slott,
    const float* __restrict__ slotg) {
  int cnt = TDIM, base = 0, e = 0;
  if constexpr (GATHER) {
    e = blockIdx.z;
    cnt = counts[e];
    base = offs[e];
    if ((int)(blockIdx.y * 128) >= cnt) return;
  }
  const int m0 = blockIdx.y * 128, n0 = blockIdx.x * 128;
  const _Float16* __restrict__ W = w2g + (size_t)e * HDIM * FDIM;

  __shared__ _Float16 As[128 * 64];
  __shared__ _Float16 Bs[128 * 64];

  const int tid = threadIdx.x, lane = tid & 63, wave = tid >> 6;
  const int wm = wave >> 1, wn = wave & 1;
  const int lrow = lane & 15, quad = lane >> 4;
  const int subrow = lane >> 3, cb = lane & 7;
  const int scb = (cb ^ subrow) * 8;

  const _Float16 *gA[4], *gB[4];
#pragma unroll
  for (int it = 0; it < 4; ++it) {
    int r = (it * 4 + wave) * 8 + subrow;
    int m = m0 + r;
    int src;
    if constexpr (GATHER) src = base + (m < cnt ? m : cnt - 1);
    else src = m;
    gA[it] = act + (size_t)src * FDIM + scb;
    gB[it] = W + (size_t)(n0 + r) * FDIM + scb;
  }

  floatx4 acc[4][4] = {};
  const int s = lrow & 7;

  for (int k0 = 0; k0 < FDIM; k0 += 64) {
#pragma unroll
    for (int it = 0; it < 4; ++it) {
      const int lb = (it * 4 + wave) * 512;
      g2l16(gA[it] + k0, &As[lb]);
      g2l16(gB[it] + k0, &Bs[lb]);
    }
    __syncthreads();
#pragma unroll
    for (int kk = 0; kk < 64; kk += 32) {
      const int cb0 = (kk >> 3) + quad;
      const int co = (cb0 ^ s) * 8;
      half8 af[4], bf[4];
#pragma unroll
      for (int i = 0; i < 4; ++i)
        af[i] = *(const half8*)&As[(wm * 64 + i * 16 + lrow) * 64 + co];
#pragma unroll
      for (int i = 0; i < 4; ++i)
        bf[i] = *(const half8*)&Bs[(wn * 64 + i * 16 + lrow) * 64 + co];
#pragma unroll
      for (int ms = 0; ms < 4; ++ms)
#pragma unroll
        for (int ns = 0; ns < 4; ++ns)
          acc[ms][ns] = __builtin_amdgcn_mfma_f32_16x16x32_f16(af[ms], bf[ns], acc[ms][ns], 0, 0, 0);
    }
    __syncthreads();
  }

#pragma unroll
  for (int ms = 0; ms < 4; ++ms)
#pragma unroll
    for (int ns = 0; ns < 4; ++ns)
#pragma unroll
      for (int r = 0; r < 4; ++r) {
        float v = acc[ms][ns][r];
        int rl = wm * 64 + ms * 16 + quad * 4 + r;
        int h = n0 + wn * 64 + ns * 16 + lrow;
        int m = m0 + rl;
        if constexpr (GATHER) {
          if (m < cnt) {
            int slot = base + m;
            atomicAdd(&out[(size_t)slott[slot] * HDIM + h], v * slotg[slot]);
          }
        } else {
          out[(size_t)m * HDIM + h] = v;
        }
      }
}

// ---------------- launcher ----------------

extern "C" void kernel_launch(void* const* d_in, const int* in_sizes, int n_in,
                              void* d_out, int out_size, void* d_ws, size_t ws_size,
                              hipStream_t stream) {
  const float* x    = (const float*)d_in[0];
  const float* gw   = (const float*)d_in[1];
  const float* bias = (const float*)d_in[2];
  const float* ws1  = (const float*)d_in[3];
  const float* ws2  = (const float*)d_in[4];
  const float* ws3  = (const float*)d_in[5];
  const float* we1  = (const float*)d_in[6];
  const float* we2  = (const float*)d_in[7];
  const float* we3  = (const float*)d_in[8];
  float* out = (float*)d_out;

  char* ws = (char*)d_ws;
  _Float16* xb   = (_Float16*)(ws + WS_XB);
  _Float16* acts = (_Float16*)(ws + WS_ACT_S);
  _Float16* actr = (_Float16*)(ws + WS_ACT_R);
  int*   toke  = (int*)(ws + WS_TOKE);
  float* tokg  = (float*)(ws + WS_TOKG);
  int*   slott = (int*)(ws + WS_SLOTT);
  float* slotg = (float*)(ws + WS_SLOTG);
  int* counts  = (int*)(ws + WS_COUNTS);
  int* fill    = (int*)(ws + WS_FILL);
  int* offs    = (int*)(ws + WS_OFFS);
  _Float16* ws1h = (_Float16*)(ws + WS_WS1H);
  _Float16* ws3h = (_Float16*)(ws + WS_WS3H);
  _Float16* ws2h = (_Float16*)(ws + WS_WS2H);
  _Float16* we1h = (_Float16*)(ws + WS_WE1H);
  _Float16* we3h = (_Float16*)(ws + WS_WE3H);
  _Float16* we2h = (_Float16*)(ws + WS_WE2H);

  hipLaunchKernelGGL(zero_meta_kernel, dim3(1), dim3(64), 0, stream, counts);
  hipLaunchKernelGGL(cvt_kernel, dim3(4096), dim3(256), 0, stream, x, xb);
  hipLaunchKernelGGL(gate_kernel, dim3(1024), dim3(256), 0, stream, x, gw, bias, toke, tokg, counts);
  hipLaunchKernelGGL(offsets_kernel, dim3(1), dim3(64), 0, stream, counts, offs);
  hipLaunchKernelGGL(scatter_kernel, dim3(16), dim3(256), 0, stream, toke, tokg, offs, fill, slott, slotg);

  constexpr int GS = (FDIM * HDIM) / 2048;           // 1408
  constexpr int GR = (NEXP * FDIM * HDIM) / 2048;    // 11264
  hipLaunchKernelGGL(cvt_kernel, dim3(GS), dim3(256), 0, stream, ws1, ws1h);
  hipLaunchKernelGGL(cvt_kernel, dim3(GS), dim3(256), 0, stream, ws3, ws3h);
  hipLaunchKernelGGL(cvt_kernel, dim3(GS), dim3(256), 0, stream, ws2, ws2h);
  hipLaunchKernelGGL(cvt_kernel, dim3(GR), dim3(256), 0, stream, we1, we1h);
  hipLaunchKernelGGL(cvt_kernel, dim3(GR), dim3(256), 0, stream, we3, we3h);
  hipLaunchKernelGGL(cvt_kernel, dim3(GR), dim3(256), 0, stream, we2, we2h);

  hipLaunchKernelGGL((up_kernel<false>), dim3(FDIM / 128, TDIM / 128, 1), dim3(256), 0, stream,
                     xb, ws1h, ws3h, acts, nullptr, nullptr, nullptr);
  hipLaunchKernelGGL((up_kernel<true>), dim3(FDIM / 128, TDIM / 128, NEXP), dim3(256), 0, stream,
                     xb, we1h, we3h, actr, counts, offs, slott);
  hipLaunchKernelGGL((down_kernel<false>), dim3(HDIM / 128, TDIM / 128, 1), dim3(256), 0, stream,
                     acts, ws2h, out, nullptr, nullptr, nullptr, nullptr);
  hipLaunchKernelGGL((down_kernel<true>), dim3(HDIM / 128, TDIM / 128, NEXP), dim3(256), 0, stream,
                     actr, we2h, out, counts, offs, slott, slotg);
}